// Round 1
// baseline (263.321 us; speedup 1.0000x reference)
//
#include <hip/hip_runtime.h>
#include <math.h>

#define Hn 1024
#define Wn 2048
#define Bn 2
#define Cn 3
#define Pn 4
#define EPSf 1e-3f
#define THRf 0.5f
#define W_SEAMf 1.0f
#define W_GRADf 0.5f
#define W_LAPf 0.1f

#define NROWS ((Pn - 1) * Hn)          // 3072 candidate (seam,row) pairs
#define WS_NACT 6                      // float-index of active-row counter (uint32)
#define WS_LIST 7                      // float-index where active-row list starts
#define WS_FLOATS (WS_LIST + NROWS)    // workspace floats needed for fast path
#define ITEMS_PER_ROW (Bn * Cn * 2)    // bc-plane x column-half = 12

__device__ __forceinline__ float rl1(float x) {
    return sqrtf(fmaf(x, x, EPSf * EPSf));
}

// ---------------------------------------------------------------------------
// Phase 1: streaming mask scan. One block per (seam p, row h), 256 threads.
// Accumulates per-seam band pixel count (denominator) and compacts active
// rows into a worklist at ws[WS_LIST..].
// ---------------------------------------------------------------------------
__global__ __launch_bounds__(256) void seam_scan(const float* __restrict__ mask,
                                                 float* __restrict__ ws) {
    const int p = blockIdx.x >> 10;        // / Hn
    const int h = blockIdx.x & (Hn - 1);   // % Hn
    const size_t HW = (size_t)Hn * Wn;
    const float* m0 = mask + (size_t)p * HW + (size_t)h * Wn;
    const float* m1 = m0 + HW;

    float cnt = 0.f;
    #pragma unroll
    for (int it = 0; it < 2; ++it) {
        const int w0 = it * 1024 + (int)threadIdx.x * 4;
        const float4 a = *(const float4*)(m0 + w0);
        const float4 b = *(const float4*)(m1 + w0);
        cnt += (float)((a.x > THRf) && (b.x > THRf))
             + (float)((a.y > THRf) && (b.y > THRf))
             + (float)((a.z > THRf) && (b.z > THRf))
             + (float)((a.w > THRf) && (b.w > THRf));
    }

    #pragma unroll
    for (int off = 32; off > 0; off >>= 1) cnt += __shfl_down(cnt, off, 64);
    __shared__ float sc[4];
    const int wave = threadIdx.x >> 6;
    const int lane = threadIdx.x & 63;
    if (lane == 0) sc[wave] = cnt;
    __syncthreads();
    if (threadIdx.x == 0) {
        const float tot = sc[0] + sc[1] + sc[2] + sc[3];
        if (tot > 0.f) {
            atomicAdd(&ws[p * 2 + 1], tot);
            const unsigned idx = atomicAdd((unsigned*)ws + WS_NACT, 1u);
            ((int*)ws)[WS_LIST + idx] = blockIdx.x;   // encodes (p,h)
        }
    }
}

// ---------------------------------------------------------------------------
// Phase 2: heavy math over compacted work items.
// Work item = (active row, bc plane, column half). Grid-stride so the launch
// size is data-independent. 256 threads: each owns 4 consecutive columns of
// a 1024-column half-row.
// ---------------------------------------------------------------------------
__global__ __launch_bounds__(256) void seam_heavy(const float* __restrict__ procs,
                                                  const float* __restrict__ mask,
                                                  float* __restrict__ ws) {
    const size_t HW = (size_t)Hn * Wn;
    const unsigned nrows = ((const unsigned*)ws)[WS_NACT];
    const unsigned nitems = nrows * ITEMS_PER_ROW;
    __shared__ float sw[4];

    for (unsigned item = blockIdx.x; item < nitems; item += gridDim.x) {
        const int row  = ((const int*)ws)[WS_LIST + item / ITEMS_PER_ROW];
        const int rem  = (int)(item % ITEMS_PER_ROW);
        const int bc   = rem >> 1;
        const int half = rem & 1;
        const int p = row >> 10;
        const int h = row & (Hn - 1);

        const int w0 = half * 1024 + (int)threadIdx.x * 4;
        const float* m0 = mask + (size_t)p * HW + (size_t)h * Wn;
        const float* m1 = m0 + HW;
        const float4 ma = *(const float4*)(m0 + w0);
        const float4 mb = *(const float4*)(m1 + w0);
        bool bb[4];
        bb[0] = (ma.x > THRf) && (mb.x > THRf);
        bb[1] = (ma.y > THRf) && (mb.y > THRf);
        bb[2] = (ma.z > THRf) && (mb.z > THRf);
        bb[3] = (ma.w > THRf) && (mb.w > THRf);

        float wsum = 0.f;
        if (bb[0] | bb[1] | bb[2] | bb[3]) {
            const bool has_d = (h < Hn - 1);
            const bool has_u = (h > 0);

            const float* A  = procs + ((size_t)p * (Bn * Cn) + bc) * HW + (size_t)h * Wn;
            const float* Bp = A + (size_t)(Bn * Cn) * HW;

            // center row diff
            const float4 ac  = *(const float4*)(A + w0);
            const float4 bcv = *(const float4*)(Bp + w0);
            float dc[4] = {ac.x - bcv.x, ac.y - bcv.y, ac.z - bcv.z, ac.w - bcv.w};

            // up / down row diffs (zero-padded)
            float du[4] = {0.f, 0.f, 0.f, 0.f};
            float dd[4] = {0.f, 0.f, 0.f, 0.f};
            if (has_u) {
                const float4 au = *(const float4*)(A + w0 - Wn);
                const float4 bu = *(const float4*)(Bp + w0 - Wn);
                du[0] = au.x - bu.x; du[1] = au.y - bu.y;
                du[2] = au.z - bu.z; du[3] = au.w - bu.w;
            }
            if (has_d) {
                const float4 ad = *(const float4*)(A + w0 + Wn);
                const float4 bd = *(const float4*)(Bp + w0 + Wn);
                dd[0] = ad.x - bd.x; dd[1] = ad.y - bd.y;
                dd[2] = ad.z - bd.z; dd[3] = ad.w - bd.w;
            }

            // horizontal halo (zero-padded at global image edges)
            const float dl0 = (w0 > 0)      ? (A[w0 - 1] - Bp[w0 - 1]) : 0.f;
            const float dr3 = (w0 + 4 < Wn) ? (A[w0 + 4] - Bp[w0 + 4]) : 0.f;
            const float dl[4] = {dl0,   dc[0], dc[1], dc[2]};
            const float dr[4] = {dc[1], dc[2], dc[3], dr3};

            float sj = 0.f, sg = 0.f, sl = 0.f;
            #pragma unroll
            for (int e = 0; e < 4; ++e) {
                if (bb[e]) {
                    sj += rl1(dc[e]);
                    // grad_h: forward diff, zero-padded at bottom; diff of zeros -> rl1(0)=EPS
                    sg += has_d ? rl1(dd[e] - dc[e]) : EPSf;
                    sl += rl1(du[e] + dd[e] + dl[e] + dr[e] - 4.f * dc[e]);
                }
            }
            wsum = W_SEAMf * sj + W_GRADf * sg + W_LAPf * sl;
        }

        // block reduction (4 waves)
        #pragma unroll
        for (int off = 32; off > 0; off >>= 1) wsum += __shfl_down(wsum, off, 64);
        const int wave = threadIdx.x >> 6;
        const int lane = threadIdx.x & 63;
        if (lane == 0) sw[wave] = wsum;
        __syncthreads();
        if (threadIdx.x == 0) {
            const float t = sw[0] + sw[1] + sw[2] + sw[3];
            if (t != 0.f) atomicAdd(&ws[p * 2], t);
        }
        __syncthreads();   // protect sw[] before next grid-stride iteration
    }
}

// ---------------------------------------------------------------------------
// Fallback path (previous session's kernel) in case ws is too small for the
// worklist. One block per (seam, row), heavy work done inline.
// ---------------------------------------------------------------------------
__global__ __launch_bounds__(256) void seam_main(const float* __restrict__ procs,
                                                 const float* __restrict__ mask,
                                                 float* __restrict__ ws) {
    const int p = blockIdx.x / Hn;
    const int h = blockIdx.x % Hn;
    const size_t HW = (size_t)Hn * Wn;

    const float* m0row = mask + (size_t)p * HW + (size_t)h * Wn;
    const float* m1row = m0row + HW;
    const size_t baseA = (size_t)p * (Bn * Cn) * HW;
    const size_t dAB   = (size_t)(Bn * Cn) * HW;

    float wsum = 0.f;
    float cnt  = 0.f;

    #pragma unroll
    for (int it = 0; it < 2; ++it) {
        const int w0 = it * 1024 + (int)threadIdx.x * 4;
        const float4 ma = *(const float4*)(m0row + w0);
        const float4 mb = *(const float4*)(m1row + w0);
        bool bb[4];
        bb[0] = (ma.x > THRf) && (mb.x > THRf);
        bb[1] = (ma.y > THRf) && (mb.y > THRf);
        bb[2] = (ma.z > THRf) && (mb.z > THRf);
        bb[3] = (ma.w > THRf) && (mb.w > THRf);
        if (!(bb[0] | bb[1] | bb[2] | bb[3])) continue;

        cnt += (float)bb[0] + (float)bb[1] + (float)bb[2] + (float)bb[3];

        const bool has_d = (h < Hn - 1);
        const bool has_u = (h > 0);

        float sj = 0.f, sg = 0.f, sl = 0.f;
        #pragma unroll
        for (int bc = 0; bc < Bn * Cn; ++bc) {
            const float* A  = procs + baseA + (size_t)bc * HW + (size_t)h * Wn;
            const float* Bp = A + dAB;

            float4 ac = *(const float4*)(A + w0);
            float4 bcv = *(const float4*)(Bp + w0);
            float dc[4] = {ac.x - bcv.x, ac.y - bcv.y, ac.z - bcv.z, ac.w - bcv.w};

            float du[4] = {0.f, 0.f, 0.f, 0.f};
            float dd[4] = {0.f, 0.f, 0.f, 0.f};
            if (has_u) {
                float4 au = *(const float4*)(A + w0 - Wn);
                float4 bu = *(const float4*)(Bp + w0 - Wn);
                du[0] = au.x - bu.x; du[1] = au.y - bu.y;
                du[2] = au.z - bu.z; du[3] = au.w - bu.w;
            }
            if (has_d) {
                float4 ad = *(const float4*)(A + w0 + Wn);
                float4 bd = *(const float4*)(Bp + w0 + Wn);
                dd[0] = ad.x - bd.x; dd[1] = ad.y - bd.y;
                dd[2] = ad.z - bd.z; dd[3] = ad.w - bd.w;
            }

            float dl0 = (w0 > 0)      ? (A[w0 - 1] - Bp[w0 - 1]) : 0.f;
            float dr3 = (w0 + 4 < Wn) ? (A[w0 + 4] - Bp[w0 + 4]) : 0.f;
            float dl[4] = {dl0,   dc[0], dc[1], dc[2]};
            float dr[4] = {dc[1], dc[2], dc[3], dr3};

            #pragma unroll
            for (int e = 0; e < 4; ++e) {
                if (bb[e]) {
                    sj += rl1(dc[e]);
                    sg += has_d ? rl1(dd[e] - dc[e]) : EPSf;
                    sl += rl1(du[e] + dd[e] + dl[e] + dr[e] - 4.f * dc[e]);
                }
            }
        }
        wsum += W_SEAMf * sj + W_GRADf * sg + W_LAPf * sl;
    }

    #pragma unroll
    for (int off = 32; off > 0; off >>= 1) {
        wsum += __shfl_down(wsum, off, 64);
        cnt  += __shfl_down(cnt,  off, 64);
    }
    __shared__ float swsum[4];
    __shared__ float scnt[4];
    const int wave = threadIdx.x >> 6;
    const int lane = threadIdx.x & 63;
    if (lane == 0) { swsum[wave] = wsum; scnt[wave] = cnt; }
    __syncthreads();
    if (threadIdx.x == 0) {
        float Wt = swsum[0] + swsum[1] + swsum[2] + swsum[3];
        float Ct = scnt[0] + scnt[1] + scnt[2] + scnt[3];
        if (Wt != 0.f || Ct != 0.f) {
            atomicAdd(&ws[p * 2 + 0], Wt);
            atomicAdd(&ws[p * 2 + 1], Ct);
        }
    }
}

__global__ void seam_final(const float* __restrict__ ws, float* __restrict__ out) {
    float acc = 0.f;
    #pragma unroll
    for (int p = 0; p < Pn - 1; ++p) {
        acc += ws[2 * p] / fmaxf(ws[2 * p + 1], EPSf);
    }
    out[0] = acc;
}

extern "C" void kernel_launch(void* const* d_in, const int* in_sizes, int n_in,
                              void* d_out, int out_size, void* d_ws, size_t ws_size,
                              hipStream_t stream) {
    const float* procs = (const float*)d_in[0];  // (P,B,C,H,W) fp32
    const float* mask  = (const float*)d_in[1];  // (P,1,H,W) fp32
    float* wsf = (float*)d_ws;

    if (ws_size >= (size_t)WS_FLOATS * sizeof(float)) {
        // Fast path: compacted worklist.
        hipMemsetAsync(d_ws, 0, WS_LIST * sizeof(float), stream);
        seam_scan<<<dim3(NROWS), dim3(256), 0, stream>>>(mask, wsf);
        seam_heavy<<<dim3(2048), dim3(256), 0, stream>>>(procs, mask, wsf);
        seam_final<<<1, 1, 0, stream>>>(wsf, (float*)d_out);
    } else {
        // Fallback: previous verified single-pass kernel.
        hipMemsetAsync(d_ws, 0, 6 * sizeof(float), stream);
        seam_main<<<dim3(NROWS), dim3(256), 0, stream>>>(procs, mask, wsf);
        seam_final<<<1, 1, 0, stream>>>(wsf, (float*)d_out);
    }
}